// Round 1
// 408.726 us; speedup vs baseline: 1.1185x; 1.1185x over previous
//
#include <hip/hip_runtime.h>

// Problem constants (fixed by setup_inputs)
#define N_   32
#define C_   512
#define CM_  128
#define H_   48
#define W_   48
#define HW_  (H_*W_)
#define P_   512

typedef unsigned short ushort_t;
typedef short s8v  __attribute__((ext_vector_type(8)));   // 8 bf16 (4 VGPRs) MFMA A/B frag
typedef float f4v  __attribute__((ext_vector_type(4)));   // 4 fp32 MFMA C/D frag

// fp32 -> bf16 (round to nearest even)
__device__ __forceinline__ ushort_t f2bf(float x) {
    unsigned int u = __float_as_uint(x);
    u += 0x7fffu + ((u >> 16) & 1u);
    return (ushort_t)(u >> 16);
}

// ---------------------------------------------------------------------------
// Kernel 1: per-(n,c) plane: mean over 48x48 and 3x3 adaptive max pool (16x16
// regions). One 256-thread block per plane.
// ---------------------------------------------------------------------------
__global__ __launch_bounds__(256) void pool_kernel(const float* __restrict__ x,
                                                   float* __restrict__ meanx,
                                                   float* __restrict__ xm) {
    int plane = blockIdx.x;                 // n*C + c
    const float* base = x + (size_t)plane * HW_;
    int t = threadIdx.x;
    int r = t >> 4, cc = t & 15;            // position within 16x16 region
    float sum = 0.f;
    float mx[9];
#pragma unroll
    for (int b = 0; b < 9; ++b) {
        int h = (b / 3) * 16 + r;
        int w = (b % 3) * 16 + cc;
        float v = base[h * W_ + w];
        mx[b] = v;
        sum += v;
    }
#pragma unroll
    for (int off = 32; off > 0; off >>= 1) {
        sum += __shfl_down(sum, off);
#pragma unroll
        for (int b = 0; b < 9; ++b) mx[b] = fmaxf(mx[b], __shfl_down(mx[b], off));
    }
    __shared__ float s[4][10];
    int wave = t >> 6, lane = t & 63;
    if (lane == 0) {
#pragma unroll
        for (int b = 0; b < 9; ++b) s[wave][b] = mx[b];
        s[wave][9] = sum;
    }
    __syncthreads();
    if (t < 9) {
        float v = fmaxf(fmaxf(s[0][t], s[1][t]), fmaxf(s[2][t], s[3][t]));
        xm[(size_t)plane * 9 + t] = v;
    } else if (t == 9) {
        float v = s[0][9] + s[1][9] + s[2][9] + s[3][9];
        meanx[plane] = v * (1.0f / (float)HW_);
    }
}

// ---------------------------------------------------------------------------
// Kernel 2: per-sample branch math. gs layout: [n][18][Cm] (c contiguous).
// ---------------------------------------------------------------------------
__global__ __launch_bounds__(128) void branch_kernel(const float* __restrict__ meanx,
                                                     const float* __restrict__ xm,
                                                     const float* __restrict__ Wc,
                                                     const float* __restrict__ bc,
                                                     const float* __restrict__ Wkk,
                                                     const float* __restrict__ bkk,
                                                     float* __restrict__ gs) {
    int n = blockIdx.x;
    __shared__ float sin_[C_ * 10];
    int t = threadIdx.x;
    for (int i = t; i < C_ * 10; i += 128) {
        int c = i / 10, j = i % 10;
        sin_[i] = (j < 9) ? xm[((size_t)n * C_ + c) * 9 + j] : meanx[n * C_ + c];
    }
    __syncthreads();
    int o = t;
    float acc[10];
#pragma unroll
    for (int j = 0; j < 10; ++j) acc[j] = 0.f;
    const float* wrow = Wc + (size_t)o * C_;
    for (int c = 0; c < C_; ++c) {
        float wv = wrow[c];
        const float* in = &sin_[c * 10];
#pragma unroll
        for (int j = 0; j < 10; ++j) acc[j] += wv * in[j];
    }
    float bco = bc[o];
    float gk1 = fmaxf(acc[9] + bco, 0.f);
    size_t gbase = (size_t)n * 18 * CM_;
#pragma unroll
    for (int b = 0; b < 9; ++b) {
        gs[gbase + b * CM_ + o]       = gk1 * Wkk[b] + bkk[b];          // g_kern (no relu)
        gs[gbase + (9 + b) * CM_ + o] = fmaxf(acc[b] + bco, 0.f);       // sk (relu)
    }
}

// ---------------------------------------------------------------------------
// Kernel 3: dynW_t[n][r][o][c] (bf16, c contiguous).
// ---------------------------------------------------------------------------
__global__ __launch_bounds__(256) void dynw_kernel(const float* __restrict__ gs,
                                                   const float* __restrict__ Wck,
                                                   const float* __restrict__ bck,
                                                   ushort_t* __restrict__ dynW_t) {
    int idx = blockIdx.x * 256 + threadIdx.x;     // 589824 threads
    int c8 = idx & 15;
    int o  = (idx >> 4) & 127;
    int v  = idx >> 11;                           // n*9 + r
    int r  = v % 9;
    int n  = v / 9;
    const float* gp = gs + ((size_t)n * 18 + r) * CM_ + c8 * 8;
    float w0 = Wck[o * 2], w1 = Wck[o * 2 + 1], bk = bck[o];
    ushort_t u[8];
#pragma unroll
    for (int i = 0; i < 8; ++i) {
        float g = gp[i];
        float s = gp[9 * CM_ + i];
        u[i] = f2bf(fmaxf(w0 * g + w1 * s + bk, 0.f));
    }
    uint4 pk;
    pk.x = (unsigned)u[0] | ((unsigned)u[1] << 16);
    pk.y = (unsigned)u[2] | ((unsigned)u[3] << 16);
    pk.z = (unsigned)u[4] | ((unsigned)u[5] << 16);
    pk.w = (unsigned)u[6] | ((unsigned)u[7] << 16);
    *(uint4*)(dynW_t + (size_t)idx * 8) = pk;
}

// ---------------------------------------------------------------------------
// Kernel 3b: cast Wc (65536) and Wf (65536) to bf16, row-major unchanged.
// 4 elements per thread; 192 blocks x 256.
// ---------------------------------------------------------------------------
__global__ __launch_bounds__(256) void convw_kernel(const float* __restrict__ Wc,
                                                    const float* __restrict__ Wf,
                                                    ushort_t* __restrict__ Wc_bf,
                                                    ushort_t* __restrict__ Wf_bf) {
    int idx = blockIdx.x * 256 + threadIdx.x;     // 49152 threads x 4 elems
    float4 v;
    ushort_t* dst;
    if (idx < 16384) {
        v = ((const float4*)Wc)[idx];
        dst = Wc_bf + (size_t)idx * 4;
    } else {
        int k = idx - 16384;
        v = ((const float4*)Wf)[k];
        dst = Wf_bf + (size_t)k * 4;
    }
    uint2 pk;
    pk.x = (unsigned)f2bf(v.x) | ((unsigned)f2bf(v.y) << 16);
    pk.y = (unsigned)f2bf(v.z) | ((unsigned)f2bf(v.w) << 16);
    *(uint2*)dst = pk;
}

// ---------------------------------------------------------------------------
// Kernel 4: f = relu(Wc @ x + bc) via bf16 MFMA, output channels-last bf16
//   f_t[n][hw][o].  Block 256 thr (4 waves) = 128 o x 64 hw tile, K=512 in
//   chunks of 32. B staged through LDS with fp32->bf16 transpose; A-frags
//   read directly from L2-resident Wc_bf.
// ---------------------------------------------------------------------------
__global__ __launch_bounds__(256) void fconv_mfma(const float* __restrict__ x,
                                                  const ushort_t* __restrict__ Wc_bf,
                                                  const float* __restrict__ bc,
                                                  ushort_t* __restrict__ f_t) {
    int n = blockIdx.y;
    int hw0 = blockIdx.x * 64;
    __shared__ ushort_t Bs[64 * 40];    // [hw][c] rows of 32 c, stride 40 (80B, 16B-aligned)
    int t = threadIdx.x;
    int wave = t >> 6, lane = t & 63;
    int j = lane & 15, q = lane >> 4;
    int o_w = wave * 32;
    int sk  = t >> 4;                   // c-pair 0..15
    int shw = (t & 15) * 4;             // hw 0..60

    const s8v* A = (const s8v*)Wc_bf;   // elem addr o*512 + k -> /8 = o*64 + k/8
    f4v acc[2][4];
#pragma unroll
    for (int mt = 0; mt < 2; ++mt)
#pragma unroll
        for (int nt = 0; nt < 4; ++nt) acc[mt][nt] = (f4v){0.f, 0.f, 0.f, 0.f};

    for (int c0 = 0; c0 < C_; c0 += 32) {
        // global loads first (prefetch before barrier)
        const float* xr = x + ((size_t)n * C_ + c0 + 2 * sk) * HW_ + hw0 + shw;
        float4 v0 = *(const float4*)xr;
        float4 v1 = *(const float4*)(xr + HW_);
        __syncthreads();                // previous iter's frag reads done
        unsigned* Bw = (unsigned*)Bs;
        {
            unsigned w0 = (unsigned)f2bf(v0.x) | ((unsigned)f2bf(v1.x) << 16);
            unsigned w1 = (unsigned)f2bf(v0.y) | ((unsigned)f2bf(v1.y) << 16);
            unsigned w2 = (unsigned)f2bf(v0.z) | ((unsigned)f2bf(v1.z) << 16);
            unsigned w3 = (unsigned)f2bf(v0.w) | ((unsigned)f2bf(v1.w) << 16);
            Bw[(shw + 0) * 20 + sk] = w0;
            Bw[(shw + 1) * 20 + sk] = w1;
            Bw[(shw + 2) * 20 + sk] = w2;
            Bw[(shw + 3) * 20 + sk] = w3;
        }
        __syncthreads();
        s8v a0 = A[(size_t)(o_w + j) * 64 + (c0 >> 3) + q];
        s8v a1 = A[(size_t)(o_w + 16 + j) * 64 + (c0 >> 3) + q];
        s8v b[4];
#pragma unroll
        for (int nt = 0; nt < 4; ++nt)
            b[nt] = *(const s8v*)&Bs[(nt * 16 + j) * 40 + q * 8];
#pragma unroll
        for (int nt = 0; nt < 4; ++nt) {
            acc[0][nt] = __builtin_amdgcn_mfma_f32_16x16x32_bf16(a0, b[nt], acc[0][nt], 0, 0, 0);
            acc[1][nt] = __builtin_amdgcn_mfma_f32_16x16x32_bf16(a1, b[nt], acc[1][nt], 0, 0, 0);
        }
    }
    // epilogue: relu+bias, pack 4 consecutive o (q*4+reg) -> 8B store
#pragma unroll
    for (int mt = 0; mt < 2; ++mt) {
        int ob = o_w + mt * 16 + q * 4;
        float b4[4];
#pragma unroll
        for (int reg = 0; reg < 4; ++reg) b4[reg] = bc[ob + reg];
#pragma unroll
        for (int nt = 0; nt < 4; ++nt) {
            int hw = hw0 + nt * 16 + j;
            ushort_t u[4];
#pragma unroll
            for (int reg = 0; reg < 4; ++reg)
                u[reg] = f2bf(fmaxf(acc[mt][nt][reg] + b4[reg], 0.f));
            uint2 pk;
            pk.x = (unsigned)u[0] | ((unsigned)u[1] << 16);
            pk.y = (unsigned)u[2] | ((unsigned)u[3] << 16);
            *(uint2*)(f_t + ((size_t)n * HW_ + hw) * CM_ + ob) = pk;
        }
    }
}

// ---------------------------------------------------------------------------
// Kernel 5: dynamic 3x3 conv via MFMA bf16. REWRITTEN:
//   Block (256 thr, 4 waves) = 2 output rows x 48 w x ALL 128 o.
//   f_t rows h0-1..h0+2 staged ONCE in LDS: [4 ri][50 wi][128 c] bf16 with
//   zero-pad columns wi=0,49 (kills all bounds checks in the K-loop) and
//   XOR swizzle byte ^= (wi&7)<<4 (stride-256B ds_read_b128 would otherwise
//   be a 16-way bank conflict; swizzle makes it conflict-free).
//   A-frags (dynW, L2-resident) hoisted 18-wide per 32-c chunk for MLP.
//   Grid: 768 blocks, XCD-swizzled so XCD x owns samples [4x,4x+4) -> dynW
//   + f_t working set ~3.5 MB per XCD L2. LDS 51200B*3 = 153.6KB -> exactly
//   3 blocks/CU, all 768 blocks co-resident (12 waves/CU).
// ---------------------------------------------------------------------------
__global__ __launch_bounds__(256, 3) void dynconv_mfma(const ushort_t* __restrict__ f_t,
                                                       const ushort_t* __restrict__ dynW_t,
                                                       const float* __restrict__ b_ad,
                                                       ushort_t* __restrict__ y_bf) {
    __shared__ ushort_t Bs[4 * 50 * 128];          // 51200 B
    int bid = blockIdx.x;
    int vid = (bid & 7) * 96 + (bid >> 3);         // m157 XCD swizzle (768 % 8 == 0)
    int n   = vid / 24;
    int h0  = (vid % 24) * 2;
    int t = threadIdx.x;
    int wave = t >> 6, lane = t & 63;
    int j = lane & 15, q = lane >> 4;

    // ---- stage: zero pads wi=0,49 ----
    if (t < 128) {
        int ri = t >> 5, wi = ((t >> 4) & 1) * 49, ci = t & 15;
        int off = ((ri * 50 + wi) * 256 + ci * 16) ^ ((wi & 7) << 4);
        uint4 z; z.x = 0u; z.y = 0u; z.z = 0u; z.w = 0u;
        *(uint4*)((char*)Bs + off) = z;
    }
    // ---- stage: 4 rows x 48 w x 128 c = 3072 16B-chunks, 12 per thread ----
#pragma unroll
    for (int ri = 0; ri < 4; ++ri) {
        int h = h0 - 1 + ri;
        bool hok = (unsigned)h < (unsigned)H_;
        const uint4* src = (const uint4*)(f_t + ((size_t)n * HW_ + h * W_) * CM_);
#pragma unroll
        for (int s = 0; s < 3; ++s) {
            int c2 = s * 256 + t;                  // chunk within row, [0,768)
            int wi = (c2 >> 4) + 1, ci = c2 & 15;
            uint4 v; v.x = 0u; v.y = 0u; v.z = 0u; v.w = 0u;
            if (hok) v = src[c2];
            int off = ((ri * 50 + wi) * 256 + ci * 16) ^ ((wi & 7) << 4);
            *(uint4*)((char*)Bs + off) = v;
        }
    }
    __syncthreads();

    int ow = wave * 32;                            // this wave's 32 output channels
    const s8v* A = (const s8v*)dynW_t;
    size_t abase = ((size_t)n * 9 * 128 + ow + j) * 16 + q;

    f4v acc[2][6];                                 // [mt o-tile][nt = rl*3+wg]
#pragma unroll
    for (int mt = 0; mt < 2; ++mt)
#pragma unroll
        for (int nt = 0; nt < 6; ++nt) acc[mt][nt] = (f4v){0.f, 0.f, 0.f, 0.f};

    for (int cc = 0; cc < 4; ++cc) {               // 32-c chunks of K
        s8v a[9][2];                               // all 9 taps x 2 o-tiles hoisted
#pragma unroll
        for (int r = 0; r < 9; ++r) {
            a[r][0] = A[abase + (size_t)r * 2048 + cc * 4];
            a[r][1] = A[abase + (size_t)r * 2048 + 256 + cc * 4];
        }
#pragma unroll
        for (int ri = 0; ri < 4; ++ri) {           // LDS row (global row h0-1+ri)
#pragma unroll
            for (int dwi = 0; dwi < 3; ++dwi) {    // dw = dwi-1
                int xr = ((j + dwi) & 7) << 4;     // = ((1 + j + dw) & 7) << 4
#pragma unroll
                for (int wg = 0; wg < 3; ++wg) {
                    int wi = wg * 16 + j + dwi;    // = 1 + (wg*16+j) + dw
                    int off = ((ri * 50 + wi) * 256 + cc * 64 + q * 16) ^ xr;
                    s8v b = *(const s8v*)((const char*)Bs + off);
                    if (ri < 3) {                  // output row h0 (rl=0), dh=ri-1
                        int r = ri * 3 + dwi;
                        acc[0][wg] = __builtin_amdgcn_mfma_f32_16x16x32_bf16(a[r][0], b, acc[0][wg], 0, 0, 0);
                        acc[1][wg] = __builtin_amdgcn_mfma_f32_16x16x32_bf16(a[r][1], b, acc[1][wg], 0, 0, 0);
                    }
                    if (ri > 0) {                  // output row h0+1 (rl=1), dh=ri-2
                        int r = (ri - 1) * 3 + dwi;
                        acc[0][3 + wg] = __builtin_amdgcn_mfma_f32_16x16x32_bf16(a[r][0], b, acc[0][3 + wg], 0, 0, 0);
                        acc[1][3 + wg] = __builtin_amdgcn_mfma_f32_16x16x32_bf16(a[r][1], b, acc[1][3 + wg], 0, 0, 0);
                    }
                }
            }
        }
    }

    // epilogue: y_bf[n][hw][o] bf16, 4 consecutive o per lane -> 8B store
#pragma unroll
    for (int mt = 0; mt < 2; ++mt) {
        int ob = ow + mt * 16 + q * 4;
        float ba[4];
#pragma unroll
        for (int reg = 0; reg < 4; ++reg) ba[reg] = b_ad[ob + reg];
#pragma unroll
        for (int rl = 0; rl < 2; ++rl) {
            int h = h0 + rl;
#pragma unroll
            for (int wg = 0; wg < 3; ++wg) {
                int nt = rl * 3 + wg;
                int hw = h * W_ + wg * 16 + j;
                ushort_t u[4];
#pragma unroll
                for (int reg = 0; reg < 4; ++reg)
                    u[reg] = f2bf(acc[mt][nt][reg] + ba[reg]);
                uint2 pk;
                pk.x = (unsigned)u[0] | ((unsigned)u[1] << 16);
                pk.y = (unsigned)u[2] | ((unsigned)u[3] << 16);
                *(uint2*)(y_bf + ((size_t)n * HW_ + hw) * CM_ + ob) = pk;
            }
        }
    }
}

// ---------------------------------------------------------------------------
// Kernel 6: out = Wf @ y + bf via bf16 MFMA, no LDS (A from Wf_bf, B from
// y_bf channels-last). Block 128 thr (2 waves) = 64 p x (4 rows x 48 w).
// ---------------------------------------------------------------------------
__global__ __launch_bounds__(128) void fuse_mfma(const ushort_t* __restrict__ y_bf,
                                                 const ushort_t* __restrict__ Wf_bf,
                                                 const float* __restrict__ bf,
                                                 float* __restrict__ out) {
    int n  = blockIdx.z;
    int p0 = blockIdx.y * 64;
    int h0 = blockIdx.x * 4;
    int t = threadIdx.x;
    int wave = t >> 6, lane = t & 63;
    int j = lane & 15, q = lane >> 4;
    int rbase = h0 + wave * 2;

    const s8v* A = (const s8v*)Wf_bf;   // elem p*128 + k -> /8 = p*16 + k/8
    const s8v* B = (const s8v*)y_bf;

    f4v acc[4][6];
#pragma unroll
    for (int mt = 0; mt < 4; ++mt)
#pragma unroll
        for (int nt = 0; nt < 6; ++nt) acc[mt][nt] = (f4v){0.f, 0.f, 0.f, 0.f};

#pragma unroll
    for (int cc = 0; cc < 4; ++cc) {
        s8v a[4];
#pragma unroll
        for (int mt = 0; mt < 4; ++mt)
            a[mt] = A[(size_t)(p0 + mt * 16 + j) * 16 + cc * 4 + q];
        s8v b[6];
#pragma unroll
        for (int rl = 0; rl < 2; ++rl) {
            int h = rbase + rl;
#pragma unroll
            for (int wg = 0; wg < 3; ++wg) {
                int hw = h * W_ + wg * 16 + j;
                b[rl * 3 + wg] = B[((size_t)n * HW_ + hw) * 16 + cc * 4 + q];
            }
        }
#pragma unroll
        for (int mt = 0; mt < 4; ++mt)
#pragma unroll
            for (int nt = 0; nt < 6; ++nt)
                acc[mt][nt] = __builtin_amdgcn_mfma_f32_16x16x32_bf16(
                    a[mt], b[nt], acc[mt][nt], 0, 0, 0);
    }
    // epilogue: out[n][p][hw] fp32
#pragma unroll
    for (int mt = 0; mt < 4; ++mt) {
        int pb = p0 + mt * 16 + q * 4;
        float b4[4];
#pragma unroll
        for (int reg = 0; reg < 4; ++reg) b4[reg] = bf[pb + reg];
#pragma unroll
        for (int rl = 0; rl < 2; ++rl) {
            int h = rbase + rl;
#pragma unroll
            for (int wg = 0; wg < 3; ++wg) {
                int nt = rl * 3 + wg;
                int hw = h * W_ + wg * 16 + j;
#pragma unroll
                for (int reg = 0; reg < 4; ++reg)
                    out[((size_t)n * P_ + pb + reg) * HW_ + hw] = acc[mt][nt][reg] + b4[reg];
            }
        }
    }
}

// ---------------------------------------------------------------------------
// Launch. Workspace layout (bytes):
//   meanx f32 @0 (65536) | xm f32 @65536 (589824) | gs f32 @655360 (294912)
//   dynW_t bf16 @950272 (9437184) | f_t bf16 @10387456 (18874368)
//   y_bf bf16 @29261824 (18874368) | Wc_bf @48136192 (131072)
//   Wf_bf @48267264 (131072)  -> total ~46.2 MB
// ---------------------------------------------------------------------------
extern "C" void kernel_launch(void* const* d_in, const int* in_sizes, int n_in,
                              void* d_out, int out_size, void* d_ws, size_t ws_size,
                              hipStream_t stream) {
    const float* x    = (const float*)d_in[0];
    const float* Wc   = (const float*)d_in[1];
    const float* bc   = (const float*)d_in[2];
    const float* Wkk  = (const float*)d_in[3];
    const float* bkk  = (const float*)d_in[4];
    const float* Wck  = (const float*)d_in[5];
    const float* bck  = (const float*)d_in[6];
    const float* b_ad = (const float*)d_in[7];
    const float* Wf   = (const float*)d_in[8];
    const float* bf   = (const float*)d_in[9];
    float* out = (float*)d_out;

    char* ws = (char*)d_ws;
    float*    meanx  = (float*)(ws);
    float*    xm     = (float*)(ws + 65536);
    float*    gs     = (float*)(ws + 655360);
    ushort_t* dynW_t = (ushort_t*)(ws + 950272);
    ushort_t* f_t    = (ushort_t*)(ws + 10387456);
    ushort_t* y_bf   = (ushort_t*)(ws + 29261824);
    ushort_t* Wc_bf  = (ushort_t*)(ws + 48136192);
    ushort_t* Wf_bf  = (ushort_t*)(ws + 48267264);

    hipLaunchKernelGGL(pool_kernel,    dim3(N_ * C_), dim3(256), 0, stream, x, meanx, xm);
    hipLaunchKernelGGL(branch_kernel,  dim3(N_),      dim3(128), 0, stream, meanx, xm, Wc, bc, Wkk, bkk, gs);
    hipLaunchKernelGGL(dynw_kernel,    dim3(2304),    dim3(256), 0, stream, gs, Wck, bck, dynW_t);
    hipLaunchKernelGGL(convw_kernel,   dim3(128),     dim3(256), 0, stream, Wc, Wf, Wc_bf, Wf_bf);
    hipLaunchKernelGGL(fconv_mfma,     dim3(36, 32),  dim3(256), 0, stream, x, Wc_bf, bc, f_t);
    hipLaunchKernelGGL(dynconv_mfma,   dim3(768),     dim3(256), 0, stream, f_t, dynW_t, b_ad, y_bf);
    hipLaunchKernelGGL(fuse_mfma,      dim3(12, 8, 32), dim3(128), 0, stream, y_bf, Wf_bf, bf, out);
}

// Round 2
// 390.692 us; speedup vs baseline: 1.1701x; 1.0462x over previous
//
#include <hip/hip_runtime.h>

// Problem constants (fixed by setup_inputs)
#define N_   32
#define C_   512
#define CM_  128
#define H_   48
#define W_   48
#define HW_  (H_*W_)
#define P_   512

typedef unsigned short ushort_t;
typedef short s8v  __attribute__((ext_vector_type(8)));   // 8 bf16 (4 VGPRs) MFMA A/B frag
typedef float f4v  __attribute__((ext_vector_type(4)));   // 4 fp32 MFMA C/D frag

// fp32 -> bf16 (round to nearest even)
__device__ __forceinline__ ushort_t f2bf(float x) {
    unsigned int u = __float_as_uint(x);
    u += 0x7fffu + ((u >> 16) & 1u);
    return (ushort_t)(u >> 16);
}

// ---------------------------------------------------------------------------
// Kernel 1: per-(n,c) plane: mean over 48x48 and 3x3 adaptive max pool (16x16
// regions). One 256-thread block per plane. Tail blocks (>= N_*C_) perform the
// Wc/Wf fp32->bf16 cast (merged former convw_kernel, saves one launch).
// ---------------------------------------------------------------------------
__global__ __launch_bounds__(256) void pool_kernel(const float* __restrict__ x,
                                                   float* __restrict__ meanx,
                                                   float* __restrict__ xm,
                                                   const float* __restrict__ Wc,
                                                   const float* __restrict__ Wf,
                                                   ushort_t* __restrict__ Wc_bf,
                                                   ushort_t* __restrict__ Wf_bf) {
    if (blockIdx.x >= N_ * C_) {
        // ---- convw tail: cast Wc (65536) and Wf (65536) to bf16 ----
        int idx = (blockIdx.x - N_ * C_) * 256 + threadIdx.x;   // [0, 49152)
        float4 v;
        ushort_t* dst;
        if (idx < 16384) {
            v = ((const float4*)Wc)[idx];
            dst = Wc_bf + (size_t)idx * 4;
        } else {
            int k = idx - 16384;
            v = ((const float4*)Wf)[k];
            dst = Wf_bf + (size_t)k * 4;
        }
        uint2 pk;
        pk.x = (unsigned)f2bf(v.x) | ((unsigned)f2bf(v.y) << 16);
        pk.y = (unsigned)f2bf(v.z) | ((unsigned)f2bf(v.w) << 16);
        *(uint2*)dst = pk;
        return;
    }
    int plane = blockIdx.x;                 // n*C + c
    const float* base = x + (size_t)plane * HW_;
    int t = threadIdx.x;
    int r = t >> 4, cc = t & 15;            // position within 16x16 region
    float sum = 0.f;
    float mx[9];
#pragma unroll
    for (int b = 0; b < 9; ++b) {
        int h = (b / 3) * 16 + r;
        int w = (b % 3) * 16 + cc;
        float v = base[h * W_ + w];
        mx[b] = v;
        sum += v;
    }
#pragma unroll
    for (int off = 32; off > 0; off >>= 1) {
        sum += __shfl_down(sum, off);
#pragma unroll
        for (int b = 0; b < 9; ++b) mx[b] = fmaxf(mx[b], __shfl_down(mx[b], off));
    }
    __shared__ float s[4][10];
    int wave = t >> 6, lane = t & 63;
    if (lane == 0) {
#pragma unroll
        for (int b = 0; b < 9; ++b) s[wave][b] = mx[b];
        s[wave][9] = sum;
    }
    __syncthreads();
    if (t < 9) {
        float v = fmaxf(fmaxf(s[0][t], s[1][t]), fmaxf(s[2][t], s[3][t]));
        xm[(size_t)plane * 9 + t] = v;
    } else if (t == 9) {
        float v = s[0][9] + s[1][9] + s[2][9] + s[3][9];
        meanx[plane] = v * (1.0f / (float)HW_);
    }
}

// ---------------------------------------------------------------------------
// Kernel 2 (REWRITTEN): per-sample branch math. gs layout: [n][18][Cm].
//   Old version: 128 threads/block, each walking Wc[o][c] with 2KB inter-lane
//   stride -> 128 scattered 4B loads/wave x 512 serial iters, 2% machine
//   occupancy. New: 512 threads (o = t&127, part p = t>>7 owns 128 of the 512
//   c), Wc staged through LDS in coalesced float4 chunks (stride-17 rows,
//   gcd(17,32)=1 -> conflict-free), 4 partial acc[10] reduced through LDS.
// ---------------------------------------------------------------------------
__global__ __launch_bounds__(512) void branch_kernel(const float* __restrict__ meanx,
                                                     const float* __restrict__ xm,
                                                     const float* __restrict__ Wc,
                                                     const float* __restrict__ bc,
                                                     const float* __restrict__ Wkk,
                                                     const float* __restrict__ bkk,
                                                     float* __restrict__ gs) {
    int n = blockIdx.x;
    __shared__ float sin_[C_ * 10];         // 20480 B
    __shared__ float Ws[4][128][17];        // 34816 B (padded: stride 17)
    int t = threadIdx.x;
    for (int i = t; i < C_ * 10; i += 512) {
        int c = i / 10, j = i % 10;
        sin_[i] = (j < 9) ? xm[((size_t)n * C_ + c) * 9 + j] : meanx[n * C_ + c];
    }
    int o = t & 127, p = t >> 7;
    float acc[10];
#pragma unroll
    for (int j = 0; j < 10; ++j) acc[j] = 0.f;

    for (int s = 0; s < 8; ++s) {           // 16 c per part per step
        __syncthreads();                    // sin_ ready (s=0) / Ws reads done (s>0)
        // stage Ws[chunk][o][0..15] = Wc[o][chunk*128 + s*16 ..+16], coalesced f4
#pragma unroll
        for (int k = 0; k < 4; ++k) {
            int f = t + k * 512;            // float4 id in [0, 2048)
            int chunk = f >> 9, oo = (f >> 2) & 127, col4 = f & 3;
            float4 v = *(const float4*)(Wc + (size_t)oo * C_ + chunk * 128 + s * 16 + col4 * 4);
            *(float4*)&Ws[chunk][oo][col4 * 4] = v;
        }
        __syncthreads();
        int cbase = p * 128 + s * 16;
#pragma unroll
        for (int cc = 0; cc < 16; ++cc) {
            float wv = Ws[p][o][cc];
            const float* in = &sin_[(cbase + cc) * 10];
#pragma unroll
            for (int j = 0; j < 10; ++j) acc[j] += wv * in[j];
        }
    }
    // reduce 4 partials through LDS (reuse Ws: 5120 floats needed, 8704 avail)
    __syncthreads();
    float* red = (float*)Ws;
#pragma unroll
    for (int j = 0; j < 10; ++j) red[t * 10 + j] = acc[j];
    __syncthreads();
    if (t < 128) {
        float a[10];
#pragma unroll
        for (int j = 0; j < 10; ++j)
            a[j] = red[t * 10 + j] + red[1280 + t * 10 + j]
                 + red[2560 + t * 10 + j] + red[3840 + t * 10 + j];
        float bco = bc[t];
        float gk1 = fmaxf(a[9] + bco, 0.f);
        size_t gbase = (size_t)n * 18 * CM_;
#pragma unroll
        for (int b = 0; b < 9; ++b) {
            gs[gbase + b * CM_ + t]       = gk1 * Wkk[b] + bkk[b];      // g_kern (no relu)
            gs[gbase + (9 + b) * CM_ + t] = fmaxf(a[b] + bco, 0.f);     // sk (relu)
        }
    }
}

// ---------------------------------------------------------------------------
// Kernel 3: dynW_t[n][r][o][c] (bf16, c contiguous).
// ---------------------------------------------------------------------------
__global__ __launch_bounds__(256) void dynw_kernel(const float* __restrict__ gs,
                                                   const float* __restrict__ Wck,
                                                   const float* __restrict__ bck,
                                                   ushort_t* __restrict__ dynW_t) {
    int idx = blockIdx.x * 256 + threadIdx.x;     // 589824 threads
    int c8 = idx & 15;
    int o  = (idx >> 4) & 127;
    int v  = idx >> 11;                           // n*9 + r
    int r  = v % 9;
    int n  = v / 9;
    const float* gp = gs + ((size_t)n * 18 + r) * CM_ + c8 * 8;
    float w0 = Wck[o * 2], w1 = Wck[o * 2 + 1], bk = bck[o];
    ushort_t u[8];
#pragma unroll
    for (int i = 0; i < 8; ++i) {
        float g = gp[i];
        float s = gp[9 * CM_ + i];
        u[i] = f2bf(fmaxf(w0 * g + w1 * s + bk, 0.f));
    }
    uint4 pk;
    pk.x = (unsigned)u[0] | ((unsigned)u[1] << 16);
    pk.y = (unsigned)u[2] | ((unsigned)u[3] << 16);
    pk.z = (unsigned)u[4] | ((unsigned)u[5] << 16);
    pk.w = (unsigned)u[6] | ((unsigned)u[7] << 16);
    *(uint4*)(dynW_t + (size_t)idx * 8) = pk;
}

// ---------------------------------------------------------------------------
// Kernel 4: f = relu(Wc @ x + bc) via bf16 MFMA, output channels-last bf16
//   f_t[n][hw][o].  Block 256 thr (4 waves) = 128 o x 64 hw tile, K=512 in
//   chunks of 32. B staged through LDS with fp32->bf16 transpose; A-frags
//   read directly from L2-resident Wc_bf.
// ---------------------------------------------------------------------------
__global__ __launch_bounds__(256) void fconv_mfma(const float* __restrict__ x,
                                                  const ushort_t* __restrict__ Wc_bf,
                                                  const float* __restrict__ bc,
                                                  ushort_t* __restrict__ f_t) {
    int n = blockIdx.y;
    int hw0 = blockIdx.x * 64;
    __shared__ ushort_t Bs[64 * 40];    // [hw][c] rows of 32 c, stride 40 (80B, 16B-aligned)
    int t = threadIdx.x;
    int wave = t >> 6, lane = t & 63;
    int j = lane & 15, q = lane >> 4;
    int o_w = wave * 32;
    int sk  = t >> 4;                   // c-pair 0..15
    int shw = (t & 15) * 4;             // hw 0..60

    const s8v* A = (const s8v*)Wc_bf;   // elem addr o*512 + k -> /8 = o*64 + k/8
    f4v acc[2][4];
#pragma unroll
    for (int mt = 0; mt < 2; ++mt)
#pragma unroll
        for (int nt = 0; nt < 4; ++nt) acc[mt][nt] = (f4v){0.f, 0.f, 0.f, 0.f};

    for (int c0 = 0; c0 < C_; c0 += 32) {
        // global loads first (prefetch before barrier)
        const float* xr = x + ((size_t)n * C_ + c0 + 2 * sk) * HW_ + hw0 + shw;
        float4 v0 = *(const float4*)xr;
        float4 v1 = *(const float4*)(xr + HW_);
        __syncthreads();                // previous iter's frag reads done
        unsigned* Bw = (unsigned*)Bs;
        {
            unsigned w0 = (unsigned)f2bf(v0.x) | ((unsigned)f2bf(v1.x) << 16);
            unsigned w1 = (unsigned)f2bf(v0.y) | ((unsigned)f2bf(v1.y) << 16);
            unsigned w2 = (unsigned)f2bf(v0.z) | ((unsigned)f2bf(v1.z) << 16);
            unsigned w3 = (unsigned)f2bf(v0.w) | ((unsigned)f2bf(v1.w) << 16);
            Bw[(shw + 0) * 20 + sk] = w0;
            Bw[(shw + 1) * 20 + sk] = w1;
            Bw[(shw + 2) * 20 + sk] = w2;
            Bw[(shw + 3) * 20 + sk] = w3;
        }
        __syncthreads();
        s8v a0 = A[(size_t)(o_w + j) * 64 + (c0 >> 3) + q];
        s8v a1 = A[(size_t)(o_w + 16 + j) * 64 + (c0 >> 3) + q];
        s8v b[4];
#pragma unroll
        for (int nt = 0; nt < 4; ++nt)
            b[nt] = *(const s8v*)&Bs[(nt * 16 + j) * 40 + q * 8];
#pragma unroll
        for (int nt = 0; nt < 4; ++nt) {
            acc[0][nt] = __builtin_amdgcn_mfma_f32_16x16x32_bf16(a0, b[nt], acc[0][nt], 0, 0, 0);
            acc[1][nt] = __builtin_amdgcn_mfma_f32_16x16x32_bf16(a1, b[nt], acc[1][nt], 0, 0, 0);
        }
    }
    // epilogue: relu+bias, pack 4 consecutive o (q*4+reg) -> 8B store
#pragma unroll
    for (int mt = 0; mt < 2; ++mt) {
        int ob = o_w + mt * 16 + q * 4;
        float b4[4];
#pragma unroll
        for (int reg = 0; reg < 4; ++reg) b4[reg] = bc[ob + reg];
#pragma unroll
        for (int nt = 0; nt < 4; ++nt) {
            int hw = hw0 + nt * 16 + j;
            ushort_t u[4];
#pragma unroll
            for (int reg = 0; reg < 4; ++reg)
                u[reg] = f2bf(fmaxf(acc[mt][nt][reg] + b4[reg], 0.f));
            uint2 pk;
            pk.x = (unsigned)u[0] | ((unsigned)u[1] << 16);
            pk.y = (unsigned)u[2] | ((unsigned)u[3] << 16);
            *(uint2*)(f_t + ((size_t)n * HW_ + hw) * CM_ + ob) = pk;
        }
    }
}

// ---------------------------------------------------------------------------
// Kernel 5: dynamic 3x3 conv via MFMA bf16.
//   Block (256 thr, 4 waves) = 2 output rows x 48 w x ALL 128 o.
//   f_t rows h0-1..h0+2 staged ONCE in LDS: [4 ri][50 wi][128 c] bf16 with
//   zero-pad columns wi=0,49 (kills all bounds checks in the K-loop) and
//   XOR swizzle byte ^= (wi&7)<<4 (stride-256B ds_read_b128 would otherwise
//   be a 16-way bank conflict; swizzle makes it conflict-free).
//   A-frags (dynW, L2-resident) hoisted 18-wide per 32-c chunk for MLP.
//   Grid: 768 blocks, XCD-swizzled so XCD x owns samples [4x,4x+4) -> dynW
//   + f_t working set ~3.5 MB per XCD L2. LDS 51200B*3 = 153.6KB -> exactly
//   3 blocks/CU, all 768 blocks co-resident (12 waves/CU).
// ---------------------------------------------------------------------------
__global__ __launch_bounds__(256, 3) void dynconv_mfma(const ushort_t* __restrict__ f_t,
                                                       const ushort_t* __restrict__ dynW_t,
                                                       const float* __restrict__ b_ad,
                                                       ushort_t* __restrict__ y_bf) {
    __shared__ ushort_t Bs[4 * 50 * 128];          // 51200 B
    int bid = blockIdx.x;
    int vid = (bid & 7) * 96 + (bid >> 3);         // m157 XCD swizzle (768 % 8 == 0)
    int n   = vid / 24;
    int h0  = (vid % 24) * 2;
    int t = threadIdx.x;
    int wave = t >> 6, lane = t & 63;
    int j = lane & 15, q = lane >> 4;

    // ---- stage: zero pads wi=0,49 ----
    if (t < 128) {
        int ri = t >> 5, wi = ((t >> 4) & 1) * 49, ci = t & 15;
        int off = ((ri * 50 + wi) * 256 + ci * 16) ^ ((wi & 7) << 4);
        uint4 z; z.x = 0u; z.y = 0u; z.z = 0u; z.w = 0u;
        *(uint4*)((char*)Bs + off) = z;
    }
    // ---- stage: 4 rows x 48 w x 128 c = 3072 16B-chunks, 12 per thread ----
#pragma unroll
    for (int ri = 0; ri < 4; ++ri) {
        int h = h0 - 1 + ri;
        bool hok = (unsigned)h < (unsigned)H_;
        const uint4* src = (const uint4*)(f_t + ((size_t)n * HW_ + h * W_) * CM_);
#pragma unroll
        for (int s = 0; s < 3; ++s) {
            int c2 = s * 256 + t;                  // chunk within row, [0,768)
            int wi = (c2 >> 4) + 1, ci = c2 & 15;
            uint4 v; v.x = 0u; v.y = 0u; v.z = 0u; v.w = 0u;
            if (hok) v = src[c2];
            int off = ((ri * 50 + wi) * 256 + ci * 16) ^ ((wi & 7) << 4);
            *(uint4*)((char*)Bs + off) = v;
        }
    }
    __syncthreads();

    int ow = wave * 32;                            // this wave's 32 output channels
    const s8v* A = (const s8v*)dynW_t;
    size_t abase = ((size_t)n * 9 * 128 + ow + j) * 16 + q;

    f4v acc[2][6];                                 // [mt o-tile][nt = rl*3+wg]
#pragma unroll
    for (int mt = 0; mt < 2; ++mt)
#pragma unroll
        for (int nt = 0; nt < 6; ++nt) acc[mt][nt] = (f4v){0.f, 0.f, 0.f, 0.f};

    for (int cc = 0; cc < 4; ++cc) {               // 32-c chunks of K
        s8v a[9][2];                               // all 9 taps x 2 o-tiles hoisted
#pragma unroll
        for (int r = 0; r < 9; ++r) {
            a[r][0] = A[abase + (size_t)r * 2048 + cc * 4];
            a[r][1] = A[abase + (size_t)r * 2048 + 256 + cc * 4];
        }
#pragma unroll
        for (int ri = 0; ri < 4; ++ri) {           // LDS row (global row h0-1+ri)
#pragma unroll
            for (int dwi = 0; dwi < 3; ++dwi) {    // dw = dwi-1
                int xr = ((j + dwi) & 7) << 4;     // = ((1 + j + dw) & 7) << 4
#pragma unroll
                for (int wg = 0; wg < 3; ++wg) {
                    int wi = wg * 16 + j + dwi;    // = 1 + (wg*16+j) + dw
                    int off = ((ri * 50 + wi) * 256 + cc * 64 + q * 16) ^ xr;
                    s8v b = *(const s8v*)((const char*)Bs + off);
                    if (ri < 3) {                  // output row h0 (rl=0), dh=ri-1
                        int r = ri * 3 + dwi;
                        acc[0][wg] = __builtin_amdgcn_mfma_f32_16x16x32_bf16(a[r][0], b, acc[0][wg], 0, 0, 0);
                        acc[1][wg] = __builtin_amdgcn_mfma_f32_16x16x32_bf16(a[r][1], b, acc[1][wg], 0, 0, 0);
                    }
                    if (ri > 0) {                  // output row h0+1 (rl=1), dh=ri-2
                        int r = (ri - 1) * 3 + dwi;
                        acc[0][3 + wg] = __builtin_amdgcn_mfma_f32_16x16x32_bf16(a[r][0], b, acc[0][3 + wg], 0, 0, 0);
                        acc[1][3 + wg] = __builtin_amdgcn_mfma_f32_16x16x32_bf16(a[r][1], b, acc[1][3 + wg], 0, 0, 0);
                    }
                }
            }
        }
    }

    // epilogue: y_bf[n][hw][o] bf16, 4 consecutive o per lane -> 8B store
#pragma unroll
    for (int mt = 0; mt < 2; ++mt) {
        int ob = ow + mt * 16 + q * 4;
        float ba[4];
#pragma unroll
        for (int reg = 0; reg < 4; ++reg) ba[reg] = b_ad[ob + reg];
#pragma unroll
        for (int rl = 0; rl < 2; ++rl) {
            int h = h0 + rl;
#pragma unroll
            for (int wg = 0; wg < 3; ++wg) {
                int nt = rl * 3 + wg;
                int hw = h * W_ + wg * 16 + j;
                ushort_t u[4];
#pragma unroll
                for (int reg = 0; reg < 4; ++reg)
                    u[reg] = f2bf(acc[mt][nt][reg] + ba[reg]);
                uint2 pk;
                pk.x = (unsigned)u[0] | ((unsigned)u[1] << 16);
                pk.y = (unsigned)u[2] | ((unsigned)u[3] << 16);
                *(uint2*)(y_bf + ((size_t)n * HW_ + hw) * CM_ + ob) = pk;
            }
        }
    }
}

// ---------------------------------------------------------------------------
// Kernel 6: out = Wf @ y + bf via bf16 MFMA, no LDS (A from Wf_bf, B from
// y_bf channels-last). Block 128 thr (2 waves) = 64 p x (4 rows x 48 w).
// ---------------------------------------------------------------------------
__global__ __launch_bounds__(128) void fuse_mfma(const ushort_t* __restrict__ y_bf,
                                                 const ushort_t* __restrict__ Wf_bf,
                                                 const float* __restrict__ bf,
                                                 float* __restrict__ out) {
    int n  = blockIdx.z;
    int p0 = blockIdx.y * 64;
    int h0 = blockIdx.x * 4;
    int t = threadIdx.x;
    int wave = t >> 6, lane = t & 63;
    int j = lane & 15, q = lane >> 4;
    int rbase = h0 + wave * 2;

    const s8v* A = (const s8v*)Wf_bf;   // elem p*128 + k -> /8 = p*16 + k/8
    const s8v* B = (const s8v*)y_bf;

    f4v acc[4][6];
#pragma unroll
    for (int mt = 0; mt < 4; ++mt)
#pragma unroll
        for (int nt = 0; nt < 6; ++nt) acc[mt][nt] = (f4v){0.f, 0.f, 0.f, 0.f};

#pragma unroll
    for (int cc = 0; cc < 4; ++cc) {
        s8v a[4];
#pragma unroll
        for (int mt = 0; mt < 4; ++mt)
            a[mt] = A[(size_t)(p0 + mt * 16 + j) * 16 + cc * 4 + q];
        s8v b[6];
#pragma unroll
        for (int rl = 0; rl < 2; ++rl) {
            int h = rbase + rl;
#pragma unroll
            for (int wg = 0; wg < 3; ++wg) {
                int hw = h * W_ + wg * 16 + j;
                b[rl * 3 + wg] = B[((size_t)n * HW_ + hw) * 16 + cc * 4 + q];
            }
        }
#pragma unroll
        for (int mt = 0; mt < 4; ++mt)
#pragma unroll
            for (int nt = 0; nt < 6; ++nt)
                acc[mt][nt] = __builtin_amdgcn_mfma_f32_16x16x32_bf16(
                    a[mt], b[nt], acc[mt][nt], 0, 0, 0);
    }
    // epilogue: out[n][p][hw] fp32
#pragma unroll
    for (int mt = 0; mt < 4; ++mt) {
        int pb = p0 + mt * 16 + q * 4;
        float b4[4];
#pragma unroll
        for (int reg = 0; reg < 4; ++reg) b4[reg] = bf[pb + reg];
#pragma unroll
        for (int rl = 0; rl < 2; ++rl) {
            int h = rbase + rl;
#pragma unroll
            for (int wg = 0; wg < 3; ++wg) {
                int nt = rl * 3 + wg;
                int hw = h * W_ + wg * 16 + j;
#pragma unroll
                for (int reg = 0; reg < 4; ++reg)
                    out[((size_t)n * P_ + pb + reg) * HW_ + hw] = acc[mt][nt][reg] + b4[reg];
            }
        }
    }
}

// ---------------------------------------------------------------------------
// Launch. Workspace layout (bytes):
//   meanx f32 @0 (65536) | xm f32 @65536 (589824) | gs f32 @655360 (294912)
//   dynW_t bf16 @950272 (9437184) | f_t bf16 @10387456 (18874368)
//   y_bf bf16 @29261824 (18874368) | Wc_bf @48136192 (131072)
//   Wf_bf @48267264 (131072)  -> total ~46.2 MB
// ---------------------------------------------------------------------------
extern "C" void kernel_launch(void* const* d_in, const int* in_sizes, int n_in,
                              void* d_out, int out_size, void* d_ws, size_t ws_size,
                              hipStream_t stream) {
    const float* x    = (const float*)d_in[0];
    const float* Wc   = (const float*)d_in[1];
    const float* bc   = (const float*)d_in[2];
    const float* Wkk  = (const float*)d_in[3];
    const float* bkk  = (const float*)d_in[4];
    const float* Wck  = (const float*)d_in[5];
    const float* bck  = (const float*)d_in[6];
    const float* b_ad = (const float*)d_in[7];
    const float* Wf   = (const float*)d_in[8];
    const float* bf   = (const float*)d_in[9];
    float* out = (float*)d_out;

    char* ws = (char*)d_ws;
    float*    meanx  = (float*)(ws);
    float*    xm     = (float*)(ws + 65536);
    float*    gs     = (float*)(ws + 655360);
    ushort_t* dynW_t = (ushort_t*)(ws + 950272);
    ushort_t* f_t    = (ushort_t*)(ws + 10387456);
    ushort_t* y_bf   = (ushort_t*)(ws + 29261824);
    ushort_t* Wc_bf  = (ushort_t*)(ws + 48136192);
    ushort_t* Wf_bf  = (ushort_t*)(ws + 48267264);

    hipLaunchKernelGGL(pool_kernel,    dim3(N_ * C_ + 192), dim3(256), 0, stream,
                       x, meanx, xm, Wc, Wf, Wc_bf, Wf_bf);
    hipLaunchKernelGGL(branch_kernel,  dim3(N_),      dim3(512), 0, stream, meanx, xm, Wc, bc, Wkk, bkk, gs);
    hipLaunchKernelGGL(dynw_kernel,    dim3(2304),    dim3(256), 0, stream, gs, Wck, bck, dynW_t);
    hipLaunchKernelGGL(fconv_mfma,     dim3(36, 32),  dim3(256), 0, stream, x, Wc_bf, bc, f_t);
    hipLaunchKernelGGL(dynconv_mfma,   dim3(768),     dim3(256), 0, stream, f_t, dynW_t, b_ad, y_bf);
    hipLaunchKernelGGL(fuse_mfma,      dim3(12, 8, 32), dim3(128), 0, stream, y_bf, Wf_bf, bf, out);
}